// Round 4
// baseline (117.013 us; speedup 1.0000x reference)
//
#include <hip/hip_runtime.h>
#include <hip/hip_bf16.h>

// ---------------------------------------------------------------------------
// LearnedMeans: 2-NN distances (queries=learned_means vs {true_means, X_train})
// + statistics. R4 structure:
//   1) convert_norms_kernel: f32 -> bf16 copy of all matrices + row sq-norms
//   2) dist_mfma_kernel: 128x128 tile, BK=32, 2-phase double-buffered LDS
//      (stage t+1 BEFORE computing t; one barrier per K-step), global_load_lds
//      16B staging, XOR swizzle chunk^=(row>>1)&3 on 64B rows (inverse on the
//      per-lane global source, same XOR on ds_read; 2-way bank alias = free).
//      R3 bug fixed: no runtime-indexed pointer arrays, <=8 live fragments
//      (R3 spilled to scratch: WRITE_SIZE 144MB, MfmaUtil 9.4%).
//   3) reduce_top2_kernel: wave-per-query chunk merge
//   4) stats_kernel: counts/means/percentiles
// Fallback to the verified R2 path if ws_size < ~23.7 MB.
// ---------------------------------------------------------------------------

#define DIM 512
#define M_Q 1024
#define P_TM 4096
#define P_XT 16384
#define P_ALL (P_TM + P_XT)          // 20480
#define NROWS_ALL (M_Q + P_ALL)      // 21504

#define BM 128
#define BN 128
#define BK 32
#define NSTEP (DIM / BK)             // 16
#define CHUNK 64
#define NCHUNK_TM (P_TM / CHUNK)     // 64
#define NCHUNK_TOT (P_ALL / CHUNK)   // 320
#define BIGF 3.402823466e38f

typedef __bf16 bf16x8 __attribute__((ext_vector_type(8)));
typedef float f32x4 __attribute__((ext_vector_type(4)));
typedef unsigned short u16x8 __attribute__((ext_vector_type(8)));

__device__ __forceinline__ unsigned short f2bf(float f) {
    unsigned int u = __float_as_uint(f);
    unsigned int r = (u + 0x7fffu + ((u >> 16) & 1u)) >> 16;
    return (unsigned short)r;
}

__device__ __forceinline__ void merge1(float v, float& d1, float& d2) {
    if (v < d1) { d2 = d1; d1 = v; }
    else if (v < d2) { d2 = v; }
}

__device__ __forceinline__ void top2_shfl16(float& d1, float& d2) {
    #pragma unroll
    for (int off = 1; off < 16; off <<= 1) {
        float o1 = __shfl_xor(d1, off);
        float o2 = __shfl_xor(d2, off);
        float n1 = fminf(d1, o1);
        float n2 = fminf(fmaxf(d1, o1), fminf(d2, o2));
        d1 = n1; d2 = n2;
    }
}

__device__ __forceinline__ void async_copy16(const void* g, void* l) {
    __builtin_amdgcn_global_load_lds(
        (const __attribute__((address_space(1))) void*)g,
        (__attribute__((address_space(3))) void*)l,
        16, 0, 0);
}

// ---------------------------------------------------------------------------
// Pass 1: f32 -> bf16 + squared norms. One wave per row (512 elems, 8/lane).
// ---------------------------------------------------------------------------
__global__ __launch_bounds__(256) void convert_norms_kernel(
    const float* __restrict__ Q, const float* __restrict__ TMat,
    const float* __restrict__ XT,
    unsigned short* __restrict__ Qb, unsigned short* __restrict__ Db,
    float* __restrict__ qn, float* __restrict__ dn)
{
    const int wid = threadIdx.x >> 6;
    const int lane = threadIdx.x & 63;
    const int row = blockIdx.x * 4 + wid;

    const float* src;
    unsigned short* dst;
    float* ndst;
    if (row < M_Q) {
        src = Q + (size_t)row * DIM; dst = Qb + (size_t)row * DIM; ndst = qn + row;
    } else {
        int r = row - M_Q;
        src = (row < M_Q + P_TM) ? (TMat + (size_t)r * DIM)
                                 : (XT + (size_t)(row - (M_Q + P_TM)) * DIM);
        dst = Db + (size_t)r * DIM; ndst = dn + r;
    }

    const float* p = src + lane * 8;
    float4 v0 = *(const float4*)p;
    float4 v1 = *(const float4*)(p + 4);
    float s = v0.x*v0.x + v0.y*v0.y + v0.z*v0.z + v0.w*v0.w
            + v1.x*v1.x + v1.y*v1.y + v1.z*v1.z + v1.w*v1.w;

    u16x8 o;
    o[0]=f2bf(v0.x); o[1]=f2bf(v0.y); o[2]=f2bf(v0.z); o[3]=f2bf(v0.w);
    o[4]=f2bf(v1.x); o[5]=f2bf(v1.y); o[6]=f2bf(v1.z); o[7]=f2bf(v1.w);
    *(u16x8*)(dst + lane * 8) = o;

    #pragma unroll
    for (int off = 32; off > 0; off >>= 1) s += __shfl_xor(s, off);
    if (lane == 0) *ndst = s;
}

// ---------------------------------------------------------------------------
// Pass 2: MFMA distance + per-64-col-chunk top-2. See header comment.
// LDS tile layout: [128 rows][64 B], row r's 16B chunk c stored at c^((r>>1)&3).
// Staging: global_load_lds writes linearly; inverse XOR folded into per-lane
// global source. ds_read applies the same XOR.
// ---------------------------------------------------------------------------
__global__ __launch_bounds__(256) void dist_mfma_kernel(
    const unsigned short* __restrict__ Qb,   // [M_Q][DIM] bf16
    const unsigned short* __restrict__ Db,   // [P_ALL][DIM] bf16
    const float* __restrict__ qn,            // [M_Q]
    const float* __restrict__ dn,            // [P_ALL]
    float* __restrict__ partial)             // [M_Q][NCHUNK_TOT][2]
{
    __shared__ __align__(16) unsigned short As[2][BM * BK];  // 2 x 8 KB
    __shared__ __align__(16) unsigned short Bs[2][BN * BK];  // 2 x 8 KB

    const int tid  = threadIdx.x;
    const int lane = tid & 63;
    const int wid  = tid >> 6;          // 0..3
    const int wr   = wid >> 1;          // 0..1
    const int wc   = wid & 1;           // 0..1
    const int mBase = blockIdx.y * BM;
    const int nBase = blockIdx.x * BN;

    // --- staging addresses (all named scalars: NO runtime-indexed arrays) ---
    // slab s covers rows [s*64, s*64+64); lane writes phys byte
    // s*4096 + wid*1024 + lane*16 -> row = s*64 + wid*16 + (lane>>2),
    // cphys = lane&3, clog = cphys ^ ((row>>1)&3).
    const int srowA = wid * 16 + (lane >> 2);            // row for s=0
    const int sclog = (lane & 3) ^ ((srowA >> 1) & 3);   // same for s=1 (row+64)
    const unsigned short* srcA0 = Qb + (size_t)(mBase + srowA) * DIM + sclog * 8;
    const unsigned short* srcA1 = srcA0 + (size_t)64 * DIM;
    const unsigned short* srcB0 = Db + (size_t)(nBase + srowA) * DIM + sclog * 8;
    const unsigned short* srcB1 = srcB0 + (size_t)64 * DIM;
    const int lds0 = wid * 512;          // ushort idx, slab 0 (wave-uniform)
    const int lds1 = 2048 + wid * 512;   // slab 1

    // --- ds_read fragment byte addresses ---
    int addrA[4], addrB[4];
    #pragma unroll
    for (int mi = 0; mi < 4; ++mi) {
        int rA = wr * 64 + mi * 16 + (lane & 15);
        addrA[mi] = rA * 64 + ((((lane >> 4) ^ ((rA >> 1) & 3))) << 4);
        int rB = wc * 64 + mi * 16 + (lane & 15);
        addrB[mi] = rB * 64 + ((((lane >> 4) ^ ((rB >> 1) & 3))) << 4);
    }

    f32x4 acc[4][4];
    #pragma unroll
    for (int mi = 0; mi < 4; ++mi)
        #pragma unroll
        for (int ni = 0; ni < 4; ++ni)
            #pragma unroll
            for (int i = 0; i < 4; ++i) acc[mi][ni][i] = 0.0f;

    // --- prologue: stage K-step 0 into buffer 0 ---
    async_copy16(srcA0, &As[0][lds0]);
    async_copy16(srcA1, &As[0][lds1]);
    async_copy16(srcB0, &Bs[0][lds0]);
    async_copy16(srcB1, &Bs[0][lds1]);
    __syncthreads();

    // --- 2-phase pipeline: stage t+1 into buf^1, compute t from buf ---
    #pragma unroll
    for (int t = 0; t < NSTEP; ++t) {
        const int cur = t & 1;
        if (t + 1 < NSTEP) {
            const int ks = (t + 1) * BK;
            async_copy16(srcA0 + ks, &As[cur ^ 1][lds0]);
            async_copy16(srcA1 + ks, &As[cur ^ 1][lds1]);
            async_copy16(srcB0 + ks, &Bs[cur ^ 1][lds0]);
            async_copy16(srcB1 + ks, &Bs[cur ^ 1][lds1]);
        }

        const char* ab = (const char*)&As[cur][0];
        const char* bb = (const char*)&Bs[cur][0];
        bf16x8 a0 = *(const bf16x8*)(ab + addrA[0]);
        bf16x8 a1 = *(const bf16x8*)(ab + addrA[1]);
        bf16x8 a2 = *(const bf16x8*)(ab + addrA[2]);
        bf16x8 a3 = *(const bf16x8*)(ab + addrA[3]);
        bf16x8 b0 = *(const bf16x8*)(bb + addrB[0]);
        bf16x8 b1 = *(const bf16x8*)(bb + addrB[1]);
        bf16x8 b2 = *(const bf16x8*)(bb + addrB[2]);
        bf16x8 b3 = *(const bf16x8*)(bb + addrB[3]);

        acc[0][0] = __builtin_amdgcn_mfma_f32_16x16x32_bf16(a0, b0, acc[0][0], 0, 0, 0);
        acc[0][1] = __builtin_amdgcn_mfma_f32_16x16x32_bf16(a0, b1, acc[0][1], 0, 0, 0);
        acc[0][2] = __builtin_amdgcn_mfma_f32_16x16x32_bf16(a0, b2, acc[0][2], 0, 0, 0);
        acc[0][3] = __builtin_amdgcn_mfma_f32_16x16x32_bf16(a0, b3, acc[0][3], 0, 0, 0);
        acc[1][0] = __builtin_amdgcn_mfma_f32_16x16x32_bf16(a1, b0, acc[1][0], 0, 0, 0);
        acc[1][1] = __builtin_amdgcn_mfma_f32_16x16x32_bf16(a1, b1, acc[1][1], 0, 0, 0);
        acc[1][2] = __builtin_amdgcn_mfma_f32_16x16x32_bf16(a1, b2, acc[1][2], 0, 0, 0);
        acc[1][3] = __builtin_amdgcn_mfma_f32_16x16x32_bf16(a1, b3, acc[1][3], 0, 0, 0);
        acc[2][0] = __builtin_amdgcn_mfma_f32_16x16x32_bf16(a2, b0, acc[2][0], 0, 0, 0);
        acc[2][1] = __builtin_amdgcn_mfma_f32_16x16x32_bf16(a2, b1, acc[2][1], 0, 0, 0);
        acc[2][2] = __builtin_amdgcn_mfma_f32_16x16x32_bf16(a2, b2, acc[2][2], 0, 0, 0);
        acc[2][3] = __builtin_amdgcn_mfma_f32_16x16x32_bf16(a2, b3, acc[2][3], 0, 0, 0);
        acc[3][0] = __builtin_amdgcn_mfma_f32_16x16x32_bf16(a3, b0, acc[3][0], 0, 0, 0);
        acc[3][1] = __builtin_amdgcn_mfma_f32_16x16x32_bf16(a3, b1, acc[3][1], 0, 0, 0);
        acc[3][2] = __builtin_amdgcn_mfma_f32_16x16x32_bf16(a3, b2, acc[3][2], 0, 0, 0);
        acc[3][3] = __builtin_amdgcn_mfma_f32_16x16x32_bf16(a3, b3, acc[3][3], 0, 0, 0);

        __syncthreads();   // drains vmcnt(0)+lgkmcnt(0): stage t+1 landed,
                           // everyone done reading buf cur before it's restaged
    }

    // --- epilogue: sq = q2 + d2 - 2*dot; top-2 per (row, 64-col chunk) ---
    const int g = lane >> 4;
    const int c = lane & 15;

    float q2[4][4];
    #pragma unroll
    for (int mi = 0; mi < 4; ++mi)
        #pragma unroll
        for (int r = 0; r < 4; ++r)
            q2[mi][r] = qn[mBase + wr * 64 + mi * 16 + g * 4 + r];

    float d1[4][4], d2[4][4];
    #pragma unroll
    for (int mi = 0; mi < 4; ++mi)
        #pragma unroll
        for (int r = 0; r < 4; ++r) { d1[mi][r] = BIGF; d2[mi][r] = BIGF; }

    #pragma unroll
    for (int ni = 0; ni < 4; ++ni) {
        float dd = dn[nBase + wc * 64 + ni * 16 + c];
        #pragma unroll
        for (int mi = 0; mi < 4; ++mi)
            #pragma unroll
            for (int r = 0; r < 4; ++r) {
                float sq = q2[mi][r] + dd - 2.0f * acc[mi][ni][r];
                sq = fmaxf(sq, 0.0f);
                merge1(sq, d1[mi][r], d2[mi][r]);
            }
    }

    #pragma unroll
    for (int mi = 0; mi < 4; ++mi)
        #pragma unroll
        for (int r = 0; r < 4; ++r)
            top2_shfl16(d1[mi][r], d2[mi][r]);

    if (c == 0) {
        int chunkG = blockIdx.x * 2 + wc;
        #pragma unroll
        for (int mi = 0; mi < 4; ++mi)
            #pragma unroll
            for (int r = 0; r < 4; ++r) {
                int row = mBase + wr * 64 + mi * 16 + g * 4 + r;
                size_t base = ((size_t)row * NCHUNK_TOT + chunkG) * 2;
                partial[base]     = d1[mi][r];
                partial[base + 1] = d2[mi][r];
            }
    }
}

// ---------------------------------------------------------------------------
// Pass 3: merge per-chunk top-2 partials (one wave per query).
// ---------------------------------------------------------------------------
__global__ __launch_bounds__(256) void reduce_top2_kernel(
    const float* __restrict__ partial, float* __restrict__ fin)
{
    const int wid  = threadIdx.x >> 6;
    const int lane = threadIdx.x & 63;
    const int m = blockIdx.x * 4 + wid;
    const float* p = partial + (size_t)m * (NCHUNK_TOT * 2);

    float2 v = *(const float2*)(p + 2 * lane);
    float a1 = fminf(v.x, v.y), a2 = fmaxf(v.x, v.y);
    #pragma unroll
    for (int off = 32; off > 0; off >>= 1) {
        float o1 = __shfl_xor(a1, off);
        float o2 = __shfl_xor(a2, off);
        float n1 = fminf(a1, o1);
        float n2 = fminf(fmaxf(a1, o1), fminf(a2, o2));
        a1 = n1; a2 = n2;
    }

    const float* px = p + 2 * NCHUNK_TM + lane * 8;
    float4 w0 = *(const float4*)px;
    float4 w1 = *(const float4*)(px + 4);
    float b1 = BIGF, b2 = BIGF;
    merge1(w0.x, b1, b2); merge1(w0.y, b1, b2);
    merge1(w0.z, b1, b2); merge1(w0.w, b1, b2);
    merge1(w1.x, b1, b2); merge1(w1.y, b1, b2);
    merge1(w1.z, b1, b2); merge1(w1.w, b1, b2);
    #pragma unroll
    for (int off = 32; off > 0; off >>= 1) {
        float o1 = __shfl_xor(b1, off);
        float o2 = __shfl_xor(b2, off);
        float n1 = fminf(b1, o1);
        float n2 = fminf(fmaxf(b1, o1), fminf(b2, o2));
        b1 = n1; b2 = n2;
    }

    if (lane == 0) {
        fin[m]           = sqrtf(a1);
        fin[M_Q + m]     = sqrtf(a2);
        fin[2*M_Q + m]   = sqrtf(b1);
        fin[3*M_Q + m]   = sqrtf(b2);
    }
}

// ---------------------------------------------------------------------------
// Pass 4: stats.
// ---------------------------------------------------------------------------
__device__ __forceinline__ void sort_and_pct(float* s, int t, float* dst) {
    __syncthreads();
    for (int k = 2; k <= 1024; k <<= 1) {
        for (int j = k >> 1; j > 0; j >>= 1) {
            __syncthreads();
            int ixj = t ^ j;
            if (ixj > t) {
                float a = s[t], b = s[ixj];
                bool up = ((t & k) == 0);
                if ((a > b) == up) { s[t] = b; s[ixj] = a; }
            }
        }
    }
    __syncthreads();
    if (t < 5) {
        const float P[5] = {10.f, 25.f, 50.f, 75.f, 90.f};
        float q = P[t] * 1023.0f / 100.0f;
        int lo = (int)q;
        float fr = q - (float)lo;
        dst[t] = s[lo] + fr * (s[lo + 1] - s[lo]);
    }
    __syncthreads();
}

__global__ __launch_bounds__(1024) void stats_kernel(
    const float* __restrict__ fin, float* __restrict__ out)
{
    __shared__ float s[1024];
    __shared__ float red[16][6];
    const int t = threadIdx.x;

    float m1 = fin[t];
    float m2 = fin[1024 + t];
    float s1 = fin[2048 + t];
    float s2 = fin[3072 + t];

    const float T = 1.0f / 3.0f;
    float v[6];
    v[0] = (m1 < T * s1 && m1 < T * m2) ? 1.0f : 0.0f;
    v[1] = (s1 < T * m1 && s1 < T * s2) ? 1.0f : 0.0f;
    v[2] = m1; v[3] = s1; v[4] = m2; v[5] = s2;

    #pragma unroll
    for (int off = 32; off > 0; off >>= 1)
        #pragma unroll
        for (int i = 0; i < 6; ++i) v[i] += __shfl_xor(v[i], off);

    int lane = t & 63, wid = t >> 6;
    if (lane == 0) {
        #pragma unroll
        for (int i = 0; i < 6; ++i) red[wid][i] = v[i];
    }
    __syncthreads();
    if (t == 0) {
        float a[6] = {0, 0, 0, 0, 0, 0};
        for (int w = 0; w < 16; ++w)
            for (int i = 0; i < 6; ++i) a[i] += red[w][i];
        out[0] = a[0];
        out[1] = a[1];
        out[2] = a[2] / 1024.0f;
        out[3] = a[3] / 1024.0f;
        out[4] = a[4] / 1024.0f;
        out[5] = a[5] / 1024.0f;
    }

    s[t] = m1;
    sort_and_pct(s, t, out + 6);
    s[t] = s1;
    sort_and_pct(s, t, out + 11);
}

// ---------------------------------------------------------------------------
// Fallback path (verified R2 kernels) — used only if ws_size is too small.
// ---------------------------------------------------------------------------
__global__ __launch_bounds__(256) void norms_kernel_fb(
    const float* __restrict__ src, float* __restrict__ dst, int nrows)
{
    int wid = threadIdx.x >> 6;
    int lane = threadIdx.x & 63;
    int row = blockIdx.x * 4 + wid;
    if (row >= nrows) return;
    const float* p = src + (size_t)row * DIM + lane * 8;
    float4 v0 = *(const float4*)p;
    float4 v1 = *(const float4*)(p + 4);
    float s = v0.x*v0.x + v0.y*v0.y + v0.z*v0.z + v0.w*v0.w
            + v1.x*v1.x + v1.y*v1.y + v1.z*v1.z + v1.w*v1.w;
    #pragma unroll
    for (int off = 32; off > 0; off >>= 1) s += __shfl_xor(s, off);
    if (lane == 0) dst[row] = s;
}

__global__ __launch_bounds__(256) void dist_top2_kernel_fb(
    const float* __restrict__ Q, const float* __restrict__ Dset,
    const float* __restrict__ qn, const float* __restrict__ dn,
    float* __restrict__ partial, int chunkGlobalOffset)
{
    __shared__ __align__(16) unsigned short As[64][40];
    __shared__ __align__(16) unsigned short Bs[64][40];

    const int tid  = threadIdx.x;
    const int lane = tid & 63;
    const int wid  = tid >> 6;
    const int mBase = blockIdx.y * 64;
    const int nBase = blockIdx.x * 64;

    const int srow = tid >> 2;
    const int skc  = (tid & 3) * 8;

    const float* qrow = Q    + (size_t)(mBase + srow) * DIM + skc;
    const float* drow = Dset + (size_t)(nBase + srow) * DIM + skc;

    f32x4 acc[4];
    #pragma unroll
    for (int nt = 0; nt < 4; ++nt)
        #pragma unroll
        for (int i = 0; i < 4; ++i) acc[nt][i] = 0.0f;

    const int frow = lane & 15;
    const int fk   = (lane >> 4) * 8;

    for (int ks = 0; ks < DIM; ks += 32) {
        float4 a0 = *(const float4*)(qrow + ks);
        float4 a1 = *(const float4*)(qrow + ks + 4);
        float4 b0 = *(const float4*)(drow + ks);
        float4 b1 = *(const float4*)(drow + ks + 4);

        u16x8 va, vb;
        va[0]=f2bf(a0.x); va[1]=f2bf(a0.y); va[2]=f2bf(a0.z); va[3]=f2bf(a0.w);
        va[4]=f2bf(a1.x); va[5]=f2bf(a1.y); va[6]=f2bf(a1.z); va[7]=f2bf(a1.w);
        vb[0]=f2bf(b0.x); vb[1]=f2bf(b0.y); vb[2]=f2bf(b0.z); vb[3]=f2bf(b0.w);
        vb[4]=f2bf(b1.x); vb[5]=f2bf(b1.y); vb[6]=f2bf(b1.z); vb[7]=f2bf(b1.w);

        *(u16x8*)(&As[srow][skc]) = va;
        *(u16x8*)(&Bs[srow][skc]) = vb;
        __syncthreads();

        bf16x8 af = *(const bf16x8*)(&As[wid * 16 + frow][fk]);
        #pragma unroll
        for (int nt = 0; nt < 4; ++nt) {
            bf16x8 bf = *(const bf16x8*)(&Bs[nt * 16 + frow][fk]);
            acc[nt] = __builtin_amdgcn_mfma_f32_16x16x32_bf16(af, bf, acc[nt], 0, 0, 0);
        }
        __syncthreads();
    }

    const int rbase = mBase + wid * 16 + ((lane >> 4) << 2);
    float q2[4];
    #pragma unroll
    for (int r = 0; r < 4; ++r) q2[r] = qn[rbase + r];

    float d1[4], d2[4];
    #pragma unroll
    for (int r = 0; r < 4; ++r) { d1[r] = BIGF; d2[r] = BIGF; }

    #pragma unroll
    for (int nt = 0; nt < 4; ++nt) {
        float dd = dn[nBase + nt * 16 + (lane & 15)];
        #pragma unroll
        for (int r = 0; r < 4; ++r) {
            float sq = q2[r] + dd - 2.0f * acc[nt][r];
            sq = fmaxf(sq, 0.0f);
            merge1(sq, d1[r], d2[r]);
        }
    }

    #pragma unroll
    for (int r = 0; r < 4; ++r) top2_shfl16(d1[r], d2[r]);

    if ((lane & 15) == 0) {
        int chunkG = chunkGlobalOffset + blockIdx.x;
        #pragma unroll
        for (int r = 0; r < 4; ++r) {
            size_t base = ((size_t)(rbase + r) * NCHUNK_TOT + chunkG) * 2;
            partial[base]     = d1[r];
            partial[base + 1] = d2[r];
        }
    }
}

// ---------------------------------------------------------------------------
extern "C" void kernel_launch(void* const* d_in, const int* in_sizes, int n_in,
                              void* d_out, int out_size, void* d_ws, size_t ws_size,
                              hipStream_t stream) {
    const float* Q  = (const float*)d_in[0];
    const float* TM = (const float*)d_in[1];
    const float* XT = (const float*)d_in[2];
    float* out = (float*)d_out;

    const size_t needMain =
        (size_t)M_Q * DIM * 2 + (size_t)P_ALL * DIM * 2 +
        4 * ((size_t)M_Q + P_ALL + (size_t)M_Q * NCHUNK_TOT * 2 + 4 * M_Q);

    if (ws_size >= needMain) {
        char* w = (char*)d_ws;
        unsigned short* Qb = (unsigned short*)w;
        unsigned short* Db = (unsigned short*)(w + (size_t)M_Q * DIM * 2);
        float* qn = (float*)(w + (size_t)M_Q * DIM * 2 + (size_t)P_ALL * DIM * 2);
        float* dn = qn + M_Q;
        float* partial = dn + P_ALL;
        float* fin = partial + (size_t)M_Q * NCHUNK_TOT * 2;

        convert_norms_kernel<<<dim3(NROWS_ALL / 4), 256, 0, stream>>>(
            Q, TM, XT, Qb, Db, qn, dn);
        dist_mfma_kernel<<<dim3(P_ALL / BN, M_Q / BM), 256, 0, stream>>>(
            Qb, Db, qn, dn, partial);
        reduce_top2_kernel<<<dim3(M_Q / 4), 256, 0, stream>>>(partial, fin);
        stats_kernel<<<dim3(1), 1024, 0, stream>>>(fin, out);
    } else {
        float* ws = (float*)d_ws;
        float* qn = ws;
        float* dn = ws + M_Q;
        float* partial = dn + P_ALL;
        float* fin = partial + (size_t)M_Q * NCHUNK_TOT * 2;

        norms_kernel_fb<<<dim3(M_Q / 4),  256, 0, stream>>>(Q,  qn, M_Q);
        norms_kernel_fb<<<dim3(P_TM / 4), 256, 0, stream>>>(TM, dn, P_TM);
        norms_kernel_fb<<<dim3(P_XT / 4), 256, 0, stream>>>(XT, dn + P_TM, P_XT);
        dist_top2_kernel_fb<<<dim3(P_TM / 64, M_Q / 64), 256, 0, stream>>>(
            Q, TM, qn, dn, partial, 0);
        dist_top2_kernel_fb<<<dim3(P_XT / 64, M_Q / 64), 256, 0, stream>>>(
            Q, XT, qn, dn + P_TM, partial, NCHUNK_TM);
        reduce_top2_kernel<<<dim3(M_Q / 4), 256, 0, stream>>>(partial, fin);
        stats_kernel<<<dim3(1), 1024, 0, stream>>>(fin, out);
    }
}

// Round 5
// 114.258 us; speedup vs baseline: 1.0241x; 1.0241x over previous
//
#include <hip/hip_runtime.h>
#include <hip/hip_bf16.h>

// ---------------------------------------------------------------------------
// LearnedMeans: 2-NN distances (queries=learned_means vs {true_means, X_train})
// + statistics. R5 structure:
//   1) convert_norms_kernel: f32 -> bf16 copy of all matrices + row sq-norms
//   2) dist_mfma_kernel: 128x128 tile, BK=64, SINGLE-buffered LDS (32 KB),
//      REGISTER-staged loads (T14 split: global->reg issued before MFMA phase,
//      ds_write after barrier). R3/R4's global_load_lds path showed a steady
//      144 MB/dispatch TCC write anomaly; reg-staging is both the diagnostic
//      and the fix candidate. XOR swizzle chunk^=(row&7) on 128B rows applied
//      on ds_write AND ds_read (2 lanes/bank = free). XCD-aware block remap:
//      each XCD owns a contiguous N-panel range, y-fastest, so each Db panel
//      (128 KB) is reused by all 8 M-blocks while L2-hot.
//   3) reduce_top2_kernel: wave-per-query chunk merge
//   4) stats_kernel: counts/means/percentiles
// Fallback to the verified R2 path if ws_size < ~24 MB.
// ---------------------------------------------------------------------------

#define DIM 512
#define M_Q 1024
#define P_TM 4096
#define P_XT 16384
#define P_ALL (P_TM + P_XT)          // 20480
#define NROWS_ALL (M_Q + P_ALL)      // 21504

#define BM 128
#define BN 128
#define BK 64
#define NSTEP (DIM / BK)             // 8
#define CHUNK 64
#define NCHUNK_TM (P_TM / CHUNK)     // 64
#define NCHUNK_TOT (P_ALL / CHUNK)   // 320
#define BIGF 3.402823466e38f

typedef __bf16 bf16x8 __attribute__((ext_vector_type(8)));
typedef float f32x4 __attribute__((ext_vector_type(4)));
typedef unsigned short u16x8 __attribute__((ext_vector_type(8)));

__device__ __forceinline__ unsigned short f2bf(float f) {
    unsigned int u = __float_as_uint(f);
    unsigned int r = (u + 0x7fffu + ((u >> 16) & 1u)) >> 16;
    return (unsigned short)r;
}

__device__ __forceinline__ void merge1(float v, float& d1, float& d2) {
    if (v < d1) { d2 = d1; d1 = v; }
    else if (v < d2) { d2 = v; }
}

__device__ __forceinline__ void top2_shfl16(float& d1, float& d2) {
    #pragma unroll
    for (int off = 1; off < 16; off <<= 1) {
        float o1 = __shfl_xor(d1, off);
        float o2 = __shfl_xor(d2, off);
        float n1 = fminf(d1, o1);
        float n2 = fminf(fmaxf(d1, o1), fminf(d2, o2));
        d1 = n1; d2 = n2;
    }
}

// ---------------------------------------------------------------------------
// Pass 1: f32 -> bf16 + squared norms. One wave per row (512 elems, 8/lane).
// ---------------------------------------------------------------------------
__global__ __launch_bounds__(256) void convert_norms_kernel(
    const float* __restrict__ Q, const float* __restrict__ TMat,
    const float* __restrict__ XT,
    unsigned short* __restrict__ Qb, unsigned short* __restrict__ Db,
    float* __restrict__ qn, float* __restrict__ dn)
{
    const int wid = threadIdx.x >> 6;
    const int lane = threadIdx.x & 63;
    const int row = blockIdx.x * 4 + wid;

    const float* src;
    unsigned short* dst;
    float* ndst;
    if (row < M_Q) {
        src = Q + (size_t)row * DIM; dst = Qb + (size_t)row * DIM; ndst = qn + row;
    } else {
        int r = row - M_Q;
        src = (row < M_Q + P_TM) ? (TMat + (size_t)r * DIM)
                                 : (XT + (size_t)(row - (M_Q + P_TM)) * DIM);
        dst = Db + (size_t)r * DIM; ndst = dn + r;
    }

    const float* p = src + lane * 8;
    float4 v0 = *(const float4*)p;
    float4 v1 = *(const float4*)(p + 4);
    float s = v0.x*v0.x + v0.y*v0.y + v0.z*v0.z + v0.w*v0.w
            + v1.x*v1.x + v1.y*v1.y + v1.z*v1.z + v1.w*v1.w;

    u16x8 o;
    o[0]=f2bf(v0.x); o[1]=f2bf(v0.y); o[2]=f2bf(v0.z); o[3]=f2bf(v0.w);
    o[4]=f2bf(v1.x); o[5]=f2bf(v1.y); o[6]=f2bf(v1.z); o[7]=f2bf(v1.w);
    *(u16x8*)(dst + lane * 8) = o;

    #pragma unroll
    for (int off = 32; off > 0; off >>= 1) s += __shfl_xor(s, off);
    if (lane == 0) *ndst = s;
}

// ---------------------------------------------------------------------------
// Pass 2: MFMA distance + per-64-col-chunk top-2.
// LDS: [128 rows][64 cols] bf16, row = 128 B = 8 chunks of 16 B; chunk c of
// row r stored at c ^ (r&7). Reads: 16 lanes stride-128B land on 8 phys
// chunks spread over all 32 banks, 2 lanes/bank = free.
// ---------------------------------------------------------------------------
__global__ __launch_bounds__(256) void dist_mfma_kernel(
    const unsigned short* __restrict__ Qb,   // [M_Q][DIM] bf16
    const unsigned short* __restrict__ Db,   // [P_ALL][DIM] bf16
    const float* __restrict__ qn,            // [M_Q]
    const float* __restrict__ dn,            // [P_ALL]
    float* __restrict__ partial)             // [M_Q][NCHUNK_TOT][2]
{
    __shared__ __align__(16) unsigned short As[BM * BK];  // 16 KB
    __shared__ __align__(16) unsigned short Bs[BN * BK];  // 16 KB

    const int tid  = threadIdx.x;
    const int lane = tid & 63;
    const int wid  = tid >> 6;          // 0..3
    const int wr   = wid >> 1;          // 0..1
    const int wc   = wid & 1;           // 0..1

    // --- XCD-aware remap: XCD k owns N-panels [k*20, k*20+20), y fastest ---
    // grid = (160, 8); hw round-robins flat id across 8 XCDs.
    const int bid = blockIdx.y * gridDim.x + blockIdx.x;   // 0..1279
    const int xcd = bid & 7;
    const int j8  = bid >> 3;            // 0..159
    const int mx  = xcd * 20 + (j8 >> 3);  // N panel 0..159
    const int my  = j8 & 7;                // M panel 0..7
    const int mBase = my * BM;
    const int nBase = mx * BN;

    // --- staging: thread handles row tid>>1, chunks (tid&1)*4 .. +3 ---
    const int srow  = tid >> 1;          // 0..127
    const int shalf = tid & 1;
    const unsigned short* gA = Qb + (size_t)(mBase + srow) * DIM + shalf * 32;
    const unsigned short* gB = Db + (size_t)(nBase + srow) * DIM + shalf * 32;
    int wAddr[4];                         // ushort index; same for As and Bs
    #pragma unroll
    for (int j = 0; j < 4; ++j) {
        int c = shalf * 4 + j;
        wAddr[j] = srow * 64 + ((c ^ (srow & 7)) << 3);
    }

    // --- ds_read fragment byte addresses (kh=0; kh=1 is ^64) ---
    int rdA[4], rdB[4];
    #pragma unroll
    for (int mi = 0; mi < 4; ++mi) {
        int rA = wr * 64 + mi * 16 + (lane & 15);
        rdA[mi] = rA * 128 + ((((lane >> 4) ^ (rA & 7))) << 4);
        int rB = wc * 64 + mi * 16 + (lane & 15);
        rdB[mi] = rB * 128 + ((((lane >> 4) ^ (rB & 7))) << 4);
    }

    f32x4 acc[4][4];
    #pragma unroll
    for (int mi = 0; mi < 4; ++mi)
        #pragma unroll
        for (int ni = 0; ni < 4; ++ni)
            #pragma unroll
            for (int i = 0; i < 4; ++i) acc[mi][ni][i] = 0.0f;

    // --- prologue: stage K-step 0 ---
    u16x8 stA[4], stB[4];
    #pragma unroll
    for (int j = 0; j < 4; ++j) {
        stA[j] = *(const u16x8*)(gA + j * 8);
        stB[j] = *(const u16x8*)(gB + j * 8);
    }
    #pragma unroll
    for (int j = 0; j < 4; ++j) {
        *(u16x8*)(&As[wAddr[j]]) = stA[j];
        *(u16x8*)(&Bs[wAddr[j]]) = stB[j];
    }
    __syncthreads();

    const char* ab = (const char*)As;
    const char* bb = (const char*)Bs;

    #pragma unroll
    for (int t = 0; t < NSTEP; ++t) {
        // issue next-step global loads FIRST (latency hides under MFMA phase)
        if (t + 1 < NSTEP) {
            const int ko = (t + 1) * BK;
            #pragma unroll
            for (int j = 0; j < 4; ++j) {
                stA[j] = *(const u16x8*)(gA + ko + j * 8);
                stB[j] = *(const u16x8*)(gB + ko + j * 8);
            }
        }

        #pragma unroll
        for (int kh = 0; kh < 2; ++kh) {
            const int x = kh << 6;
            bf16x8 a0 = *(const bf16x8*)(ab + (rdA[0] ^ x));
            bf16x8 a1 = *(const bf16x8*)(ab + (rdA[1] ^ x));
            bf16x8 a2 = *(const bf16x8*)(ab + (rdA[2] ^ x));
            bf16x8 a3 = *(const bf16x8*)(ab + (rdA[3] ^ x));
            bf16x8 b0 = *(const bf16x8*)(bb + (rdB[0] ^ x));
            bf16x8 b1 = *(const bf16x8*)(bb + (rdB[1] ^ x));
            bf16x8 b2 = *(const bf16x8*)(bb + (rdB[2] ^ x));
            bf16x8 b3 = *(const bf16x8*)(bb + (rdB[3] ^ x));

            acc[0][0] = __builtin_amdgcn_mfma_f32_16x16x32_bf16(a0, b0, acc[0][0], 0, 0, 0);
            acc[0][1] = __builtin_amdgcn_mfma_f32_16x16x32_bf16(a0, b1, acc[0][1], 0, 0, 0);
            acc[0][2] = __builtin_amdgcn_mfma_f32_16x16x32_bf16(a0, b2, acc[0][2], 0, 0, 0);
            acc[0][3] = __builtin_amdgcn_mfma_f32_16x16x32_bf16(a0, b3, acc[0][3], 0, 0, 0);
            acc[1][0] = __builtin_amdgcn_mfma_f32_16x16x32_bf16(a1, b0, acc[1][0], 0, 0, 0);
            acc[1][1] = __builtin_amdgcn_mfma_f32_16x16x32_bf16(a1, b1, acc[1][1], 0, 0, 0);
            acc[1][2] = __builtin_amdgcn_mfma_f32_16x16x32_bf16(a1, b2, acc[1][2], 0, 0, 0);
            acc[1][3] = __builtin_amdgcn_mfma_f32_16x16x32_bf16(a1, b3, acc[1][3], 0, 0, 0);
            acc[2][0] = __builtin_amdgcn_mfma_f32_16x16x32_bf16(a2, b0, acc[2][0], 0, 0, 0);
            acc[2][1] = __builtin_amdgcn_mfma_f32_16x16x32_bf16(a2, b1, acc[2][1], 0, 0, 0);
            acc[2][2] = __builtin_amdgcn_mfma_f32_16x16x32_bf16(a2, b2, acc[2][2], 0, 0, 0);
            acc[2][3] = __builtin_amdgcn_mfma_f32_16x16x32_bf16(a2, b3, acc[2][3], 0, 0, 0);
            acc[3][0] = __builtin_amdgcn_mfma_f32_16x16x32_bf16(a3, b0, acc[3][0], 0, 0, 0);
            acc[3][1] = __builtin_amdgcn_mfma_f32_16x16x32_bf16(a3, b1, acc[3][1], 0, 0, 0);
            acc[3][2] = __builtin_amdgcn_mfma_f32_16x16x32_bf16(a3, b2, acc[3][2], 0, 0, 0);
            acc[3][3] = __builtin_amdgcn_mfma_f32_16x16x32_bf16(a3, b3, acc[3][3], 0, 0, 0);
        }

        __syncthreads();                 // everyone done READING LDS

        if (t + 1 < NSTEP) {
            #pragma unroll
            for (int j = 0; j < 4; ++j) {  // vmcnt wait inserted here by compiler
                *(u16x8*)(&As[wAddr[j]]) = stA[j];
                *(u16x8*)(&Bs[wAddr[j]]) = stB[j];
            }
            __syncthreads();             // LDS ready for step t+1
        }
    }

    // --- epilogue: sq = q2 + d2 - 2*dot; top-2 per (row, 64-col chunk) ---
    const int g = lane >> 4;
    const int c = lane & 15;

    float q2[4][4];
    #pragma unroll
    for (int mi = 0; mi < 4; ++mi)
        #pragma unroll
        for (int r = 0; r < 4; ++r)
            q2[mi][r] = qn[mBase + wr * 64 + mi * 16 + g * 4 + r];

    float d1[4][4], d2[4][4];
    #pragma unroll
    for (int mi = 0; mi < 4; ++mi)
        #pragma unroll
        for (int r = 0; r < 4; ++r) { d1[mi][r] = BIGF; d2[mi][r] = BIGF; }

    #pragma unroll
    for (int ni = 0; ni < 4; ++ni) {
        float dd = dn[nBase + wc * 64 + ni * 16 + c];
        #pragma unroll
        for (int mi = 0; mi < 4; ++mi)
            #pragma unroll
            for (int r = 0; r < 4; ++r) {
                float sq = q2[mi][r] + dd - 2.0f * acc[mi][ni][r];
                sq = fmaxf(sq, 0.0f);
                merge1(sq, d1[mi][r], d2[mi][r]);
            }
    }

    #pragma unroll
    for (int mi = 0; mi < 4; ++mi)
        #pragma unroll
        for (int r = 0; r < 4; ++r)
            top2_shfl16(d1[mi][r], d2[mi][r]);

    if (c == 0) {
        int chunkG = mx * 2 + wc;
        #pragma unroll
        for (int mi = 0; mi < 4; ++mi)
            #pragma unroll
            for (int r = 0; r < 4; ++r) {
                int row = mBase + wr * 64 + mi * 16 + g * 4 + r;
                size_t base = ((size_t)row * NCHUNK_TOT + chunkG) * 2;
                partial[base]     = d1[mi][r];
                partial[base + 1] = d2[mi][r];
            }
    }
}

// ---------------------------------------------------------------------------
// Pass 3: merge per-chunk top-2 partials (one wave per query).
// ---------------------------------------------------------------------------
__global__ __launch_bounds__(256) void reduce_top2_kernel(
    const float* __restrict__ partial, float* __restrict__ fin)
{
    const int wid  = threadIdx.x >> 6;
    const int lane = threadIdx.x & 63;
    const int m = blockIdx.x * 4 + wid;
    const float* p = partial + (size_t)m * (NCHUNK_TOT * 2);

    float2 v = *(const float2*)(p + 2 * lane);
    float a1 = fminf(v.x, v.y), a2 = fmaxf(v.x, v.y);
    #pragma unroll
    for (int off = 32; off > 0; off >>= 1) {
        float o1 = __shfl_xor(a1, off);
        float o2 = __shfl_xor(a2, off);
        float n1 = fminf(a1, o1);
        float n2 = fminf(fmaxf(a1, o1), fminf(a2, o2));
        a1 = n1; a2 = n2;
    }

    const float* px = p + 2 * NCHUNK_TM + lane * 8;
    float4 w0 = *(const float4*)px;
    float4 w1 = *(const float4*)(px + 4);
    float b1 = BIGF, b2 = BIGF;
    merge1(w0.x, b1, b2); merge1(w0.y, b1, b2);
    merge1(w0.z, b1, b2); merge1(w0.w, b1, b2);
    merge1(w1.x, b1, b2); merge1(w1.y, b1, b2);
    merge1(w1.z, b1, b2); merge1(w1.w, b1, b2);
    #pragma unroll
    for (int off = 32; off > 0; off >>= 1) {
        float o1 = __shfl_xor(b1, off);
        float o2 = __shfl_xor(b2, off);
        float n1 = fminf(b1, o1);
        float n2 = fminf(fmaxf(b1, o1), fminf(b2, o2));
        b1 = n1; b2 = n2;
    }

    if (lane == 0) {
        fin[m]           = sqrtf(a1);
        fin[M_Q + m]     = sqrtf(a2);
        fin[2*M_Q + m]   = sqrtf(b1);
        fin[3*M_Q + m]   = sqrtf(b2);
    }
}

// ---------------------------------------------------------------------------
// Pass 4: stats.
// ---------------------------------------------------------------------------
__device__ __forceinline__ void sort_and_pct(float* s, int t, float* dst) {
    __syncthreads();
    for (int k = 2; k <= 1024; k <<= 1) {
        for (int j = k >> 1; j > 0; j >>= 1) {
            __syncthreads();
            int ixj = t ^ j;
            if (ixj > t) {
                float a = s[t], b = s[ixj];
                bool up = ((t & k) == 0);
                if ((a > b) == up) { s[t] = b; s[ixj] = a; }
            }
        }
    }
    __syncthreads();
    if (t < 5) {
        const float P[5] = {10.f, 25.f, 50.f, 75.f, 90.f};
        float q = P[t] * 1023.0f / 100.0f;
        int lo = (int)q;
        float fr = q - (float)lo;
        dst[t] = s[lo] + fr * (s[lo + 1] - s[lo]);
    }
    __syncthreads();
}

__global__ __launch_bounds__(1024) void stats_kernel(
    const float* __restrict__ fin, float* __restrict__ out)
{
    __shared__ float s[1024];
    __shared__ float red[16][6];
    const int t = threadIdx.x;

    float m1 = fin[t];
    float m2 = fin[1024 + t];
    float s1 = fin[2048 + t];
    float s2 = fin[3072 + t];

    const float T = 1.0f / 3.0f;
    float v[6];
    v[0] = (m1 < T * s1 && m1 < T * m2) ? 1.0f : 0.0f;
    v[1] = (s1 < T * m1 && s1 < T * s2) ? 1.0f : 0.0f;
    v[2] = m1; v[3] = s1; v[4] = m2; v[5] = s2;

    #pragma unroll
    for (int off = 32; off > 0; off >>= 1)
        #pragma unroll
        for (int i = 0; i < 6; ++i) v[i] += __shfl_xor(v[i], off);

    int lane = t & 63, wid = t >> 6;
    if (lane == 0) {
        #pragma unroll
        for (int i = 0; i < 6; ++i) red[wid][i] = v[i];
    }
    __syncthreads();
    if (t == 0) {
        float a[6] = {0, 0, 0, 0, 0, 0};
        for (int w = 0; w < 16; ++w)
            for (int i = 0; i < 6; ++i) a[i] += red[w][i];
        out[0] = a[0];
        out[1] = a[1];
        out[2] = a[2] / 1024.0f;
        out[3] = a[3] / 1024.0f;
        out[4] = a[4] / 1024.0f;
        out[5] = a[5] / 1024.0f;
    }

    s[t] = m1;
    sort_and_pct(s, t, out + 6);
    s[t] = s1;
    sort_and_pct(s, t, out + 11);
}

// ---------------------------------------------------------------------------
// Fallback path (verified R2 kernels) — used only if ws_size is too small.
// ---------------------------------------------------------------------------
__global__ __launch_bounds__(256) void norms_kernel_fb(
    const float* __restrict__ src, float* __restrict__ dst, int nrows)
{
    int wid = threadIdx.x >> 6;
    int lane = threadIdx.x & 63;
    int row = blockIdx.x * 4 + wid;
    if (row >= nrows) return;
    const float* p = src + (size_t)row * DIM + lane * 8;
    float4 v0 = *(const float4*)p;
    float4 v1 = *(const float4*)(p + 4);
    float s = v0.x*v0.x + v0.y*v0.y + v0.z*v0.z + v0.w*v0.w
            + v1.x*v1.x + v1.y*v1.y + v1.z*v1.z + v1.w*v1.w;
    #pragma unroll
    for (int off = 32; off > 0; off >>= 1) s += __shfl_xor(s, off);
    if (lane == 0) dst[row] = s;
}

__global__ __launch_bounds__(256) void dist_top2_kernel_fb(
    const float* __restrict__ Q, const float* __restrict__ Dset,
    const float* __restrict__ qn, const float* __restrict__ dn,
    float* __restrict__ partial, int chunkGlobalOffset)
{
    __shared__ __align__(16) unsigned short As[64][40];
    __shared__ __align__(16) unsigned short Bs[64][40];

    const int tid  = threadIdx.x;
    const int lane = tid & 63;
    const int wid  = tid >> 6;
    const int mBase = blockIdx.y * 64;
    const int nBase = blockIdx.x * 64;

    const int srow = tid >> 2;
    const int skc  = (tid & 3) * 8;

    const float* qrow = Q    + (size_t)(mBase + srow) * DIM + skc;
    const float* drow = Dset + (size_t)(nBase + srow) * DIM + skc;

    f32x4 acc[4];
    #pragma unroll
    for (int nt = 0; nt < 4; ++nt)
        #pragma unroll
        for (int i = 0; i < 4; ++i) acc[nt][i] = 0.0f;

    const int frow = lane & 15;
    const int fk   = (lane >> 4) * 8;

    for (int ks = 0; ks < DIM; ks += 32) {
        float4 a0 = *(const float4*)(qrow + ks);
        float4 a1 = *(const float4*)(qrow + ks + 4);
        float4 b0 = *(const float4*)(drow + ks);
        float4 b1 = *(const float4*)(drow + ks + 4);

        u16x8 va, vb;
        va[0]=f2bf(a0.x); va[1]=f2bf(a0.y); va[2]=f2bf(a0.z); va[3]=f2bf(a0.w);
        va[4]=f2bf(a1.x); va[5]=f2bf(a1.y); va[6]=f2bf(a1.z); va[7]=f2bf(a1.w);
        vb[0]=f2bf(b0.x); vb[1]=f2bf(b0.y); vb[2]=f2bf(b0.z); vb[3]=f2bf(b0.w);
        vb[4]=f2bf(b1.x); vb[5]=f2bf(b1.y); vb[6]=f2bf(b1.z); vb[7]=f2bf(b1.w);

        *(u16x8*)(&As[srow][skc]) = va;
        *(u16x8*)(&Bs[srow][skc]) = vb;
        __syncthreads();

        bf16x8 af = *(const bf16x8*)(&As[wid * 16 + frow][fk]);
        #pragma unroll
        for (int nt = 0; nt < 4; ++nt) {
            bf16x8 bf = *(const bf16x8*)(&Bs[nt * 16 + frow][fk]);
            acc[nt] = __builtin_amdgcn_mfma_f32_16x16x32_bf16(af, bf, acc[nt], 0, 0, 0);
        }
        __syncthreads();
    }

    const int rbase = mBase + wid * 16 + ((lane >> 4) << 2);
    float q2[4];
    #pragma unroll
    for (int r = 0; r < 4; ++r) q2[r] = qn[rbase + r];

    float d1[4], d2[4];
    #pragma unroll
    for (int r = 0; r < 4; ++r) { d1[r] = BIGF; d2[r] = BIGF; }

    #pragma unroll
    for (int nt = 0; nt < 4; ++nt) {
        float dd = dn[nBase + nt * 16 + (lane & 15)];
        #pragma unroll
        for (int r = 0; r < 4; ++r) {
            float sq = q2[r] + dd - 2.0f * acc[nt][r];
            sq = fmaxf(sq, 0.0f);
            merge1(sq, d1[r], d2[r]);
        }
    }

    #pragma unroll
    for (int r = 0; r < 4; ++r) top2_shfl16(d1[r], d2[r]);

    if ((lane & 15) == 0) {
        int chunkG = chunkGlobalOffset + blockIdx.x;
        #pragma unroll
        for (int r = 0; r < 4; ++r) {
            size_t base = ((size_t)(rbase + r) * NCHUNK_TOT + chunkG) * 2;
            partial[base]     = d1[r];
            partial[base + 1] = d2[r];
        }
    }
}

// ---------------------------------------------------------------------------
extern "C" void kernel_launch(void* const* d_in, const int* in_sizes, int n_in,
                              void* d_out, int out_size, void* d_ws, size_t ws_size,
                              hipStream_t stream) {
    const float* Q  = (const float*)d_in[0];
    const float* TM = (const float*)d_in[1];
    const float* XT = (const float*)d_in[2];
    float* out = (float*)d_out;

    const size_t needMain =
        (size_t)M_Q * DIM * 2 + (size_t)P_ALL * DIM * 2 +
        4 * ((size_t)M_Q + P_ALL + (size_t)M_Q * NCHUNK_TOT * 2 + 4 * M_Q);

    if (ws_size >= needMain) {
        char* w = (char*)d_ws;
        unsigned short* Qb = (unsigned short*)w;
        unsigned short* Db = (unsigned short*)(w + (size_t)M_Q * DIM * 2);
        float* qn = (float*)(w + (size_t)M_Q * DIM * 2 + (size_t)P_ALL * DIM * 2);
        float* dn = qn + M_Q;
        float* partial = dn + P_ALL;
        float* fin = partial + (size_t)M_Q * NCHUNK_TOT * 2;

        convert_norms_kernel<<<dim3(NROWS_ALL / 4), 256, 0, stream>>>(
            Q, TM, XT, Qb, Db, qn, dn);
        dist_mfma_kernel<<<dim3(P_ALL / BN, M_Q / BM), 256, 0, stream>>>(
            Qb, Db, qn, dn, partial);
        reduce_top2_kernel<<<dim3(M_Q / 4), 256, 0, stream>>>(partial, fin);
        stats_kernel<<<dim3(1), 1024, 0, stream>>>(fin, out);
    } else {
        float* ws = (float*)d_ws;
        float* qn = ws;
        float* dn = ws + M_Q;
        float* partial = dn + P_ALL;
        float* fin = partial + (size_t)M_Q * NCHUNK_TOT * 2;

        norms_kernel_fb<<<dim3(M_Q / 4),  256, 0, stream>>>(Q,  qn, M_Q);
        norms_kernel_fb<<<dim3(P_TM / 4), 256, 0, stream>>>(TM, dn, P_TM);
        norms_kernel_fb<<<dim3(P_XT / 4), 256, 0, stream>>>(XT, dn + P_TM, P_XT);
        dist_top2_kernel_fb<<<dim3(P_TM / 64, M_Q / 64), 256, 0, stream>>>(
            Q, TM, qn, dn, partial, 0);
        dist_top2_kernel_fb<<<dim3(P_XT / 64, M_Q / 64), 256, 0, stream>>>(
            Q, XT, qn, dn + P_TM, partial, NCHUNK_TM);
        reduce_top2_kernel<<<dim3(M_Q / 4), 256, 0, stream>>>(partial, fin);
        stats_kernel<<<dim3(1), 1024, 0, stream>>>(fin, out);
    }
}